// Round 1
// baseline (13795.616 us; speedup 1.0000x reference)
//
#include <hip/hip_runtime.h>
#include <math.h>

#define SEQ 256
#define BATCH 64
#define HID 1024
#define VOCAB 4000

// ---------------------------------------------------------------------------
// GRU step: grid = 256 blocks (4 hidden columns each), block = 256 threads
// (4 waves). Wave w handles column j = blockIdx.x*4 + w for all 3 gates;
// lane = batch index b. h_prev staged in LDS (padded stride 132 -> the
// 8-way serialization equals the b128 minimum, no extra conflicts).
// W_hh rows are wave-uniform loads -> single line broadcast per instr.
// ---------------------------------------------------------------------------
__global__ __launch_bounds__(256) void gru_step_kernel(
    const float* __restrict__ h_prev,   // (64, 1024)
    float*       __restrict__ h_out,    // (64, 1024)
    const float* __restrict__ W_hh,     // (3072, 1024)
    const float* __restrict__ W_ih,     // (3072, 4000)
    const float* __restrict__ b_ih,     // (3072,)
    const float* __restrict__ b_hh,     // (3072,)
    const int*   __restrict__ ids,      // (64, 256)
    int t)
{
    constexpr int KT = 128;
    constexpr int HPAD = KT + 4;            // 132 floats: bank-spread + 16B aligned
    __shared__ float hs[BATCH * HPAD];      // 64*132*4 = 33.8 KB

    const int tid  = threadIdx.x;
    const int wave = tid >> 6;
    const int b    = tid & 63;              // lane = batch
    const int j    = blockIdx.x * 4 + wave; // hidden column, 0..1023

    const float* __restrict__ wr = W_hh + (size_t)j * HID;
    const float* __restrict__ wz = W_hh + (size_t)(HID + j) * HID;
    const float* __restrict__ wn = W_hh + (size_t)(2 * HID + j) * HID;

    float accr = 0.f, accz = 0.f, accn = 0.f;

    for (int kc = 0; kc < HID; kc += KT) {
        __syncthreads();   // protect previous chunk's reads
        // stage h[0:64][kc:kc+KT]: 64*128 floats = 2048 float4, 8 per thread
        #pragma unroll
        for (int i = 0; i < 8; ++i) {
            int idx = tid + i * 256;        // 0..2047
            int row = idx >> 5;             // 32 float4 per row
            int c4  = idx & 31;
            *(float4*)(&hs[row * HPAD + c4 * 4]) =
                *(const float4*)(h_prev + (size_t)row * HID + kc + c4 * 4);
        }
        __syncthreads();

        #pragma unroll 8
        for (int kk = 0; kk < KT; kk += 4) {
            float4 hv = *(const float4*)(&hs[b * HPAD + kk]);
            float4 w0 = *(const float4*)(wr + kc + kk);
            float4 w1 = *(const float4*)(wz + kc + kk);
            float4 w2 = *(const float4*)(wn + kc + kk);
            accr += hv.x * w0.x + hv.y * w0.y + hv.z * w0.z + hv.w * w0.w;
            accz += hv.x * w1.x + hv.y * w1.y + hv.z * w1.z + hv.w * w1.w;
            accn += hv.x * w2.x + hv.y * w2.y + hv.z * w2.z + hv.w * w2.w;
        }
    }

    // epilogue: input projection gather + gate math
    const int id = ids[b * SEQ + t];
    const float xr = W_ih[(size_t)j * VOCAB + id]             + b_ih[j];
    const float xz = W_ih[(size_t)(HID + j) * VOCAB + id]     + b_ih[HID + j];
    const float xn = W_ih[(size_t)(2 * HID + j) * VOCAB + id] + b_ih[2 * HID + j];
    const float hr  = accr + b_hh[j];
    const float hz  = accz + b_hh[HID + j];
    const float hn_ = accn + b_hh[2 * HID + j];

    const float r = 1.0f / (1.0f + expf(-(xr + hr)));
    const float z = 1.0f / (1.0f + expf(-(xz + hz)));
    const float n = tanhf(xn + r * hn_);
    const float hp = h_prev[(size_t)b * HID + j];
    h_out[(size_t)b * HID + j] = (1.0f - z) * n + z * hp;
}

// ---------------------------------------------------------------------------
// Output GEMM: C[m][n] = sum_k A[m][k]*B[n][k] + bias[n]
// A = gru_out (16384 x 1024), B = W_out (4000 x 1024), C = logits.
// 128x128 tile, BK=32, 8x8 micro-tile, LDS-transposed tiles -> b128 reads.
// ---------------------------------------------------------------------------
__global__ __launch_bounds__(256) void out_gemm_kernel(
    const float* __restrict__ A,
    const float* __restrict__ B,
    const float* __restrict__ bias,
    float*       __restrict__ C)
{
    constexpr int BM = 128, BN = 128, BK = 32, LP = BM + 4;
    __shared__ float As[BK][LP];   // As[k][m]
    __shared__ float Bs[BK][LP];   // Bs[k][n]

    const int tid = threadIdx.x;
    const int m0 = blockIdx.x * BM;
    const int n0 = blockIdx.y * BN;
    const int tx = tid & 15;       // n-group (consecutive lanes -> consecutive n)
    const int ty = tid >> 4;       // m-group

    float acc[8][8];
    #pragma unroll
    for (int i = 0; i < 8; ++i)
        #pragma unroll
        for (int jj = 0; jj < 8; ++jj) acc[i][jj] = 0.f;

    for (int kc = 0; kc < HID; kc += BK) {
        __syncthreads();
        // stage A tile transposed: 128 rows x 32 k = 1024 float4, 4/thread
        #pragma unroll
        for (int i = 0; i < 4; ++i) {
            int idx = tid + i * 256;      // 0..1023
            int row = idx >> 3;           // 8 float4 per row
            int kq  = idx & 7;
            float4 v = *(const float4*)(A + (size_t)(m0 + row) * HID + kc + kq * 4);
            As[kq * 4 + 0][row] = v.x;
            As[kq * 4 + 1][row] = v.y;
            As[kq * 4 + 2][row] = v.z;
            As[kq * 4 + 3][row] = v.w;
        }
        // stage B tile transposed, guard n >= VOCAB
        #pragma unroll
        for (int i = 0; i < 4; ++i) {
            int idx = tid + i * 256;
            int row = idx >> 3;
            int kq  = idx & 7;
            int n   = n0 + row;
            float4 v = make_float4(0.f, 0.f, 0.f, 0.f);
            if (n < VOCAB)
                v = *(const float4*)(B + (size_t)n * HID + kc + kq * 4);
            Bs[kq * 4 + 0][row] = v.x;
            Bs[kq * 4 + 1][row] = v.y;
            Bs[kq * 4 + 2][row] = v.z;
            Bs[kq * 4 + 3][row] = v.w;
        }
        __syncthreads();

        #pragma unroll
        for (int k = 0; k < BK; ++k) {
            float a[8], bb[8];
            *(float4*)&a[0]  = *(const float4*)&As[k][ty * 8];
            *(float4*)&a[4]  = *(const float4*)&As[k][ty * 8 + 4];
            *(float4*)&bb[0] = *(const float4*)&Bs[k][tx * 8];
            *(float4*)&bb[4] = *(const float4*)&Bs[k][tx * 8 + 4];
            #pragma unroll
            for (int i = 0; i < 8; ++i)
                #pragma unroll
                for (int jj = 0; jj < 8; ++jj)
                    acc[i][jj] += a[i] * bb[jj];
        }
    }

    // store: lane's n-range = n0 + tx*8 .. +8 (float4-coalesced), m = m0+ty*8+i
    #pragma unroll
    for (int i = 0; i < 8; ++i) {
        const int m = m0 + ty * 8 + i;
        const int nbase = n0 + tx * 8;
        #pragma unroll
        for (int q = 0; q < 2; ++q) {
            int n = nbase + q * 4;
            if (n + 4 <= VOCAB) {
                float4 o;
                o.x = acc[i][q * 4 + 0] + bias[n + 0];
                o.y = acc[i][q * 4 + 1] + bias[n + 1];
                o.z = acc[i][q * 4 + 2] + bias[n + 2];
                o.w = acc[i][q * 4 + 3] + bias[n + 3];
                *(float4*)(C + (size_t)m * VOCAB + n) = o;
            }
        }
    }
}

__global__ __launch_bounds__(256) void copy_hn_kernel(
    const float* __restrict__ src, float* __restrict__ dst)
{
    int i = blockIdx.x * 256 + threadIdx.x;   // 65536 total
    dst[i] = src[i];
}

extern "C" void kernel_launch(void* const* d_in, const int* in_sizes, int n_in,
                              void* d_out, int out_size, void* d_ws, size_t ws_size,
                              hipStream_t stream) {
    const int*   inputs = (const int*)d_in[0];
    const float* h0     = (const float*)d_in[1];
    const float* W_ih   = (const float*)d_in[2];
    const float* W_hh   = (const float*)d_in[3];
    const float* b_ih   = (const float*)d_in[4];
    const float* b_hh   = (const float*)d_in[5];
    const float* W_out  = (const float*)d_in[6];
    const float* b_out  = (const float*)d_in[7];
    float* out = (float*)d_out;

    float* gru_out = (float*)d_ws;   // 256 * 64 * 1024 f32 = 64 MB history

    for (int t = 0; t < SEQ; ++t) {
        const float* hp = (t == 0) ? h0 : gru_out + (size_t)(t - 1) * BATCH * HID;
        gru_step_kernel<<<256, 256, 0, stream>>>(
            hp, gru_out + (size_t)t * BATCH * HID,
            W_hh, W_ih, b_ih, b_hh, inputs, t);
    }

    out_gemm_kernel<<<dim3(128, 32), 256, 0, stream>>>(gru_out, W_out, b_out, out);

    copy_hn_kernel<<<256, 256, 0, stream>>>(
        gru_out + (size_t)(SEQ - 1) * BATCH * HID,
        out + (size_t)SEQ * BATCH * VOCAB);
}

// Round 2
// 7166.824 us; speedup vs baseline: 1.9249x; 1.9249x over previous
//
#include <hip/hip_runtime.h>
#include <math.h>

#define SEQ 256
#define BATCH 64
#define HID 1024
#define VOCAB 4000

typedef __attribute__((ext_vector_type(8))) short short8;
typedef __attribute__((ext_vector_type(4))) float f32x4;

__device__ inline unsigned short f2bf(float x) {
    unsigned int u = __builtin_bit_cast(unsigned int, x);
    unsigned int r = (u + 0x7fffu + ((u >> 16) & 1u)) >> 16;   // RNE
    return (unsigned short)r;
}
__device__ inline float bf2f(unsigned short h) {
    unsigned int u = ((unsigned int)h) << 16;
    return __builtin_bit_cast(float, u);
}

// ---------------------------------------------------------------------------
// Split f32 arrays into bf16 hi/lo pairs (W_hh, W_out, h0). Grid-stride.
// ---------------------------------------------------------------------------
__global__ __launch_bounds__(256) void split_kernel(
    const float* __restrict__ W_hh, const float* __restrict__ W_out,
    const float* __restrict__ h0,
    unsigned short* __restrict__ whh_hi, unsigned short* __restrict__ whh_lo,
    unsigned short* __restrict__ wout_hi, unsigned short* __restrict__ wout_lo,
    unsigned short* __restrict__ h0_hi, unsigned short* __restrict__ h0_lo)
{
    const int NW = 3 * HID * HID;        // 3,145,728
    const int NO = VOCAB * HID;          // 4,096,000
    const int NH = BATCH * HID;          // 65,536
    const int total = NW + NO + NH;
    for (int i = blockIdx.x * blockDim.x + threadIdx.x; i < total;
         i += gridDim.x * blockDim.x) {
        const float* src; unsigned short *dh, *dl; int off;
        if (i < NW)           { src = W_hh;  dh = whh_hi;  dl = whh_lo;  off = i; }
        else if (i < NW + NO) { src = W_out; dh = wout_hi; dl = wout_lo; off = i - NW; }
        else                  { src = h0;    dh = h0_hi;   dl = h0_lo;   off = i - NW - NO; }
        float x = src[off];
        unsigned short hi = f2bf(x);
        dh[off] = hi;
        dl[off] = f2bf(x - bf2f(hi));
    }
}

// ---------------------------------------------------------------------------
// GRU step via MFMA. Grid = 256 blocks x 64 threads (1 wave).
// Block bid: j-tile = bid>>2 (16 hidden cols), m-tile = bid&3 (16 batches).
// Wave computes three 16x16 tiles (gates r,z,n) with split-bf16 (3 MFMA each
// per K=32 chunk). Frags load straight from global (K-contiguous, 16B/lane).
// C/D layout: col = lane&15 (j), row = (lane>>4)*4 + reg (batch) -> all three
// gate accs for a given (batch,j) sit in the SAME lane: gate math is local.
// ---------------------------------------------------------------------------
__global__ __launch_bounds__(64) void gru_step_mfma(
    const unsigned short* __restrict__ ahi,   // h_{t-1} hi (64x1024)
    const unsigned short* __restrict__ alo,
    const float* __restrict__ hprev,          // h_{t-1} f32
    const unsigned short* __restrict__ whh_hi,
    const unsigned short* __restrict__ whh_lo,
    const float* __restrict__ W_ih,
    const float* __restrict__ b_ih,
    const float* __restrict__ b_hh,
    const int*   __restrict__ ids,
    float* __restrict__ hout,                 // h_t f32
    unsigned short* __restrict__ ohi,         // gru_hi + t*65536
    unsigned short* __restrict__ olo,
    int t)
{
    const int l   = threadIdx.x;
    const int jt  = blockIdx.x >> 2;
    const int mt  = blockIdx.x & 3;
    const int j0  = jt * 16, m0 = mt * 16;
    const int col = l & 15, kg = l >> 4;

    f32x4 accr = {0.f, 0.f, 0.f, 0.f};
    f32x4 accz = {0.f, 0.f, 0.f, 0.f};
    f32x4 accn = {0.f, 0.f, 0.f, 0.f};

    const size_t arow   = (size_t)(m0 + col) * HID;
    const size_t brow_r = (size_t)(j0 + col) * HID;
    const size_t brow_z = (size_t)(HID + j0 + col) * HID;
    const size_t brow_n = (size_t)(2 * HID + j0 + col) * HID;

    #pragma unroll 2
    for (int kc = 0; kc < HID; kc += 32) {
        const int ko = kc + kg * 8;
        short8 a_h  = *(const short8*)(ahi + arow + ko);
        short8 a_l  = *(const short8*)(alo + arow + ko);
        short8 br_h = *(const short8*)(whh_hi + brow_r + ko);
        short8 br_l = *(const short8*)(whh_lo + brow_r + ko);
        short8 bz_h = *(const short8*)(whh_hi + brow_z + ko);
        short8 bz_l = *(const short8*)(whh_lo + brow_z + ko);
        short8 bn_h = *(const short8*)(whh_hi + brow_n + ko);
        short8 bn_l = *(const short8*)(whh_lo + brow_n + ko);

        accr = __builtin_amdgcn_mfma_f32_16x16x32_bf16(a_h, br_h, accr, 0, 0, 0);
        accr = __builtin_amdgcn_mfma_f32_16x16x32_bf16(a_h, br_l, accr, 0, 0, 0);
        accr = __builtin_amdgcn_mfma_f32_16x16x32_bf16(a_l, br_h, accr, 0, 0, 0);

        accz = __builtin_amdgcn_mfma_f32_16x16x32_bf16(a_h, bz_h, accz, 0, 0, 0);
        accz = __builtin_amdgcn_mfma_f32_16x16x32_bf16(a_h, bz_l, accz, 0, 0, 0);
        accz = __builtin_amdgcn_mfma_f32_16x16x32_bf16(a_l, bz_h, accz, 0, 0, 0);

        accn = __builtin_amdgcn_mfma_f32_16x16x32_bf16(a_h, bn_h, accn, 0, 0, 0);
        accn = __builtin_amdgcn_mfma_f32_16x16x32_bf16(a_h, bn_l, accn, 0, 0, 0);
        accn = __builtin_amdgcn_mfma_f32_16x16x32_bf16(a_l, bn_h, accn, 0, 0, 0);
    }

    // epilogue: x_proj gather + gate math + h split-write, all lane-local
    #pragma unroll
    for (int r = 0; r < 4; ++r) {
        const int b = m0 + kg * 4 + r;
        const int j = j0 + col;
        const int id = ids[b * SEQ + t];
        const float xr = W_ih[(size_t)j * VOCAB + id]             + b_ih[j];
        const float xz = W_ih[(size_t)(HID + j) * VOCAB + id]     + b_ih[HID + j];
        const float xn = W_ih[(size_t)(2 * HID + j) * VOCAB + id] + b_ih[2 * HID + j];
        const float hr  = accr[r] + b_hh[j];
        const float hz  = accz[r] + b_hh[HID + j];
        const float hn_ = accn[r] + b_hh[2 * HID + j];
        const float rg = 1.f / (1.f + expf(-(xr + hr)));
        const float zg = 1.f / (1.f + expf(-(xz + hz)));
        const float ng = tanhf(xn + rg * hn_);
        const float hp = hprev[(size_t)b * HID + j];
        const float h  = (1.f - zg) * ng + zg * hp;
        hout[(size_t)b * HID + j] = h;
        const unsigned short hh = f2bf(h);
        ohi[(size_t)b * HID + j] = hh;
        olo[(size_t)b * HID + j] = f2bf(h - bf2f(hh));
    }
}

// ---------------------------------------------------------------------------
// Output GEMM, split-bf16 MFMA. C[m][n] = sum_k A[m][k]*B[n][k] + bias[n].
// 128x128 tile, BK=32, LDS pad LDK=40 (frag reads land 2-way = free).
// 4 waves = 2x2 quadrants of 64x64, each 4x4 16-tiles, 48 MFMA per chunk.
// ---------------------------------------------------------------------------
__global__ __launch_bounds__(256) void out_gemm_mfma(
    const unsigned short* __restrict__ Ahi_g,  // 16384 x 1024
    const unsigned short* __restrict__ Alo_g,
    const unsigned short* __restrict__ Bhi_g,  // 4000 x 1024
    const unsigned short* __restrict__ Blo_g,
    const float* __restrict__ bias,
    float* __restrict__ C)
{
    constexpr int BM = 128, BK = 32, LDK = 40;
    __shared__ unsigned short Ah[BM * LDK], Al[BM * LDK];
    __shared__ unsigned short Bh[BM * LDK], Bl[BM * LDK];

    const int tid = threadIdx.x;
    const int l = tid & 63, w = tid >> 6;
    const int wr = w >> 1, wc = w & 1;
    const int col = l & 15, kg = l >> 4;
    const int m0 = blockIdx.x * BM;
    const int n0 = blockIdx.y * BM;

    f32x4 acc[4][4];
    #pragma unroll
    for (int i = 0; i < 4; ++i)
        #pragma unroll
        for (int jt = 0; jt < 4; ++jt)
            acc[i][jt] = (f32x4){0.f, 0.f, 0.f, 0.f};

    for (int kc = 0; kc < HID; kc += BK) {
        __syncthreads();
        #pragma unroll
        for (int i = 0; i < 2; ++i) {
            const int idx = tid + i * 256;          // 0..511
            const int row = idx >> 2, kq = idx & 3;
            const int go = kc + kq * 8;
            *(short8*)(Ah + row * LDK + kq * 8) =
                *(const short8*)(Ahi_g + (size_t)(m0 + row) * HID + go);
            *(short8*)(Al + row * LDK + kq * 8) =
                *(const short8*)(Alo_g + (size_t)(m0 + row) * HID + go);
            const int n = n0 + row;
            short8 vh = {0,0,0,0,0,0,0,0}, vl = {0,0,0,0,0,0,0,0};
            if (n < VOCAB) {
                vh = *(const short8*)(Bhi_g + (size_t)n * HID + go);
                vl = *(const short8*)(Blo_g + (size_t)n * HID + go);
            }
            *(short8*)(Bh + row * LDK + kq * 8) = vh;
            *(short8*)(Bl + row * LDK + kq * 8) = vl;
        }
        __syncthreads();

        short8 af_h[4], af_l[4], bf_h[4], bf_l[4];
        #pragma unroll
        for (int i = 0; i < 4; ++i) {
            const int r = wr * 64 + i * 16 + col;
            af_h[i] = *(const short8*)(Ah + r * LDK + kg * 8);
            af_l[i] = *(const short8*)(Al + r * LDK + kg * 8);
        }
        #pragma unroll
        for (int jt = 0; jt < 4; ++jt) {
            const int r = wc * 64 + jt * 16 + col;
            bf_h[jt] = *(const short8*)(Bh + r * LDK + kg * 8);
            bf_l[jt] = *(const short8*)(Bl + r * LDK + kg * 8);
        }
        #pragma unroll
        for (int i = 0; i < 4; ++i)
            #pragma unroll
            for (int jt = 0; jt < 4; ++jt) {
                acc[i][jt] = __builtin_amdgcn_mfma_f32_16x16x32_bf16(af_h[i], bf_h[jt], acc[i][jt], 0, 0, 0);
                acc[i][jt] = __builtin_amdgcn_mfma_f32_16x16x32_bf16(af_h[i], bf_l[jt], acc[i][jt], 0, 0, 0);
                acc[i][jt] = __builtin_amdgcn_mfma_f32_16x16x32_bf16(af_l[i], bf_h[jt], acc[i][jt], 0, 0, 0);
            }
    }

    #pragma unroll
    for (int i = 0; i < 4; ++i)
        #pragma unroll
        for (int jt = 0; jt < 4; ++jt)
            #pragma unroll
            for (int r = 0; r < 4; ++r) {
                const int m = m0 + wr * 64 + i * 16 + kg * 4 + r;
                const int n = n0 + wc * 64 + jt * 16 + col;
                if (n < VOCAB)
                    C[(size_t)m * VOCAB + n] = acc[i][jt][r] + bias[n];
            }
}

__global__ __launch_bounds__(256) void copy_hn_kernel(
    const float* __restrict__ src, float* __restrict__ dst)
{
    const int i = blockIdx.x * 256 + threadIdx.x;   // 65536 total
    dst[i] = src[i];
}

extern "C" void kernel_launch(void* const* d_in, const int* in_sizes, int n_in,
                              void* d_out, int out_size, void* d_ws, size_t ws_size,
                              hipStream_t stream) {
    const int*   inputs = (const int*)d_in[0];
    const float* h0     = (const float*)d_in[1];
    const float* W_ih   = (const float*)d_in[2];
    const float* W_hh   = (const float*)d_in[3];
    const float* b_ih   = (const float*)d_in[4];
    const float* b_hh   = (const float*)d_in[5];
    const float* W_out  = (const float*)d_in[6];
    const float* b_out  = (const float*)d_in[7];
    float* out = (float*)d_out;

    // workspace layout (bytes)
    char* p = (char*)d_ws;
    unsigned short* ghi     = (unsigned short*)p; p += (size_t)SEQ * BATCH * HID * 2;  // 33.55 MB
    unsigned short* glo     = (unsigned short*)p; p += (size_t)SEQ * BATCH * HID * 2;
    unsigned short* whh_hi  = (unsigned short*)p; p += (size_t)3 * HID * HID * 2;      // 6.29 MB
    unsigned short* whh_lo  = (unsigned short*)p; p += (size_t)3 * HID * HID * 2;
    unsigned short* wout_hi = (unsigned short*)p; p += (size_t)VOCAB * HID * 2;        // 8.19 MB
    unsigned short* wout_lo = (unsigned short*)p; p += (size_t)VOCAB * HID * 2;
    unsigned short* h0_hi   = (unsigned short*)p; p += (size_t)BATCH * HID * 2;
    unsigned short* h0_lo   = (unsigned short*)p; p += (size_t)BATCH * HID * 2;
    float* hb0              = (float*)p;          p += (size_t)BATCH * HID * 4;
    float* hb1              = (float*)p;          p += (size_t)BATCH * HID * 4;

    split_kernel<<<2048, 256, 0, stream>>>(W_hh, W_out, h0,
        whh_hi, whh_lo, wout_hi, wout_lo, h0_hi, h0_lo);

    for (int t = 0; t < SEQ; ++t) {
        const unsigned short* ahi = (t == 0) ? h0_hi : ghi + (size_t)(t - 1) * BATCH * HID;
        const unsigned short* alo = (t == 0) ? h0_lo : glo + (size_t)(t - 1) * BATCH * HID;
        const float* hp = (t == 0) ? h0 : ((t - 1) & 1 ? hb1 : hb0);
        float* ho = (t & 1) ? hb1 : hb0;
        gru_step_mfma<<<256, 64, 0, stream>>>(
            ahi, alo, hp, whh_hi, whh_lo, W_ih, b_ih, b_hh, inputs,
            ho, ghi + (size_t)t * BATCH * HID, glo + (size_t)t * BATCH * HID, t);
    }

    out_gemm_mfma<<<dim3(128, 32), 256, 0, stream>>>(
        ghi, glo, wout_hi, wout_lo, b_out, out);

    copy_hn_kernel<<<256, 256, 0, stream>>>(
        hb1, out + (size_t)SEQ * BATCH * VOCAB);
}

// Round 3
// 3335.542 us; speedup vs baseline: 4.1359x; 2.1486x over previous
//
#include <hip/hip_runtime.h>
#include <math.h>

#define SEQ 256
#define BATCH 64
#define HID 1024
#define VOCAB 4000
#define H3 (3 * HID)

typedef __attribute__((ext_vector_type(8))) short short8;
typedef __attribute__((ext_vector_type(4))) float f32x4;

__device__ inline unsigned short f2bf(float x) {
    unsigned int u = __builtin_bit_cast(unsigned int, x);
    unsigned int r = (u + 0x7fffu + ((u >> 16) & 1u)) >> 16;   // RNE
    return (unsigned short)r;
}
__device__ inline float bf2f(unsigned short h) {
    unsigned int u = ((unsigned int)h) << 16;
    return __builtin_bit_cast(float, u);
}

// ---------------------------------------------------------------------------
// Split f32 arrays into bf16 hi/lo pairs (W_hh, W_out, h0). Grid-stride.
// ---------------------------------------------------------------------------
__global__ __launch_bounds__(256) void split_kernel(
    const float* __restrict__ W_hh, const float* __restrict__ W_out,
    const float* __restrict__ h0,
    unsigned short* __restrict__ whh_hi, unsigned short* __restrict__ whh_lo,
    unsigned short* __restrict__ wout_hi, unsigned short* __restrict__ wout_lo,
    unsigned short* __restrict__ h0_hi, unsigned short* __restrict__ h0_lo)
{
    const int NW = 3 * HID * HID;
    const int NO = VOCAB * HID;
    const int NH = BATCH * HID;
    const int total = NW + NO + NH;
    for (int i = blockIdx.x * blockDim.x + threadIdx.x; i < total;
         i += gridDim.x * blockDim.x) {
        const float* src; unsigned short *dh, *dl; int off;
        if (i < NW)           { src = W_hh;  dh = whh_hi;  dl = whh_lo;  off = i; }
        else if (i < NW + NO) { src = W_out; dh = wout_hi; dl = wout_lo; off = i - NW; }
        else                  { src = h0;    dh = h0_hi;   dl = h0_lo;   off = i - NW - NO; }
        float x = src[off];
        unsigned short hi = f2bf(x);
        dh[off] = hi;
        dl[off] = f2bf(x - bf2f(hi));
    }
}

// ---------------------------------------------------------------------------
// W_ih (3072 x 4000) -> W_ihT (4000 x 3072), 32x32 LDS tiles.
// Makes the per-step x_proj gather fully coalesced (row reads of W_ihT).
// ---------------------------------------------------------------------------
__global__ __launch_bounds__(256) void transpose_wih(
    const float* __restrict__ W_ih, float* __restrict__ W_ihT)
{
    __shared__ float tile[32][33];
    const int tx = threadIdx.x & 31;
    const int ty = threadIdx.x >> 5;          // 0..7
    const int r0 = blockIdx.y * 32;           // 3072-dim base
    const int c0 = blockIdx.x * 32;           // 4000-dim base
    #pragma unroll
    for (int k = 0; k < 4; ++k) {
        const int r = ty + k * 8;
        tile[r][tx] = W_ih[(size_t)(r0 + r) * VOCAB + c0 + tx];  // 4000%32==0
    }
    __syncthreads();
    #pragma unroll
    for (int k = 0; k < 4; ++k) {
        const int r = ty + k * 8;
        W_ihT[(size_t)(c0 + r) * H3 + r0 + tx] = tile[tx][r];
    }
}

// ---------------------------------------------------------------------------
// GRU step via MFMA, K-split across 8 waves. Grid = 256 blocks x 512 threads.
// Block bid: jt = bid>>2 (16 hidden cols), mt = bid&3 (16 batches).
// Wave w computes partial sums over K in [w*128, (w+1)*128) for three 16x16
// gate tiles (split-bf16, 3 MFMA per product pair). Partials reduced in LDS;
// epilogue: 1 thread = 1 output (b,j), coalesced W_ihT x_proj reads.
// ---------------------------------------------------------------------------
__global__ __launch_bounds__(512) void gru_step_mfma(
    const unsigned short* __restrict__ ahi,   // h_{t-1} hi (64x1024)
    const unsigned short* __restrict__ alo,
    const float* __restrict__ hprev,          // h_{t-1} f32
    const unsigned short* __restrict__ whh_hi,
    const unsigned short* __restrict__ whh_lo,
    const float* __restrict__ W_ihT,          // (4000, 3072)
    const float* __restrict__ b_ih,
    const float* __restrict__ b_hh,
    const int*   __restrict__ ids,
    float* __restrict__ hout,                 // h_t f32
    unsigned short* __restrict__ ohi,
    unsigned short* __restrict__ olo,
    int t)
{
    __shared__ float red[8][3][64][4];        // [wave][gate][lane][reg] 24 KB

    const int tid = threadIdx.x;
    const int w   = tid >> 6;                 // 0..7
    const int l   = tid & 63;
    const int jt  = blockIdx.x >> 2;
    const int mt  = blockIdx.x & 3;
    const int j0  = jt * 16, m0 = mt * 16;
    const int col = l & 15, kg = l >> 4;

    f32x4 accr = {0.f, 0.f, 0.f, 0.f};
    f32x4 accz = {0.f, 0.f, 0.f, 0.f};
    f32x4 accn = {0.f, 0.f, 0.f, 0.f};

    const size_t arow   = (size_t)(m0 + col) * HID;
    const size_t brow_r = (size_t)(j0 + col) * HID;
    const size_t brow_z = (size_t)(HID + j0 + col) * HID;
    const size_t brow_n = (size_t)(2 * HID + j0 + col) * HID;

    const int kbase = w * 128 + kg * 8;
    #pragma unroll 2
    for (int c = 0; c < 4; ++c) {
        const int ko = kbase + c * 32;
        short8 a_h  = *(const short8*)(ahi + arow + ko);
        short8 a_l  = *(const short8*)(alo + arow + ko);
        short8 br_h = *(const short8*)(whh_hi + brow_r + ko);
        short8 br_l = *(const short8*)(whh_lo + brow_r + ko);
        short8 bz_h = *(const short8*)(whh_hi + brow_z + ko);
        short8 bz_l = *(const short8*)(whh_lo + brow_z + ko);
        short8 bn_h = *(const short8*)(whh_hi + brow_n + ko);
        short8 bn_l = *(const short8*)(whh_lo + brow_n + ko);

        accr = __builtin_amdgcn_mfma_f32_16x16x32_bf16(a_h, br_h, accr, 0, 0, 0);
        accr = __builtin_amdgcn_mfma_f32_16x16x32_bf16(a_h, br_l, accr, 0, 0, 0);
        accr = __builtin_amdgcn_mfma_f32_16x16x32_bf16(a_l, br_h, accr, 0, 0, 0);

        accz = __builtin_amdgcn_mfma_f32_16x16x32_bf16(a_h, bz_h, accz, 0, 0, 0);
        accz = __builtin_amdgcn_mfma_f32_16x16x32_bf16(a_h, bz_l, accz, 0, 0, 0);
        accz = __builtin_amdgcn_mfma_f32_16x16x32_bf16(a_l, bz_h, accz, 0, 0, 0);

        accn = __builtin_amdgcn_mfma_f32_16x16x32_bf16(a_h, bn_h, accn, 0, 0, 0);
        accn = __builtin_amdgcn_mfma_f32_16x16x32_bf16(a_h, bn_l, accn, 0, 0, 0);
        accn = __builtin_amdgcn_mfma_f32_16x16x32_bf16(a_l, bn_h, accn, 0, 0, 0);
    }

    *(f32x4*)&red[w][0][l][0] = accr;
    *(f32x4*)&red[w][1][l][0] = accz;
    *(f32x4*)&red[w][2][l][0] = accn;
    __syncthreads();

    if (tid < 256) {
        const int bi   = tid >> 4;            // 0..15 (batch within tile)
        const int cj   = tid & 15;            // j within tile
        const int lane = (bi >> 2) * 16 + cj; // MFMA C-layout inverse
        const int rr   = bi & 3;
        float sr = 0.f, sz = 0.f, sn = 0.f;
        #pragma unroll
        for (int ww = 0; ww < 8; ++ww) {
            sr += red[ww][0][lane][rr];
            sz += red[ww][1][lane][rr];
            sn += red[ww][2][lane][rr];
        }
        const int b = m0 + bi;
        const int j = j0 + cj;
        const int id = ids[b * SEQ + t];
        const float* xrow = W_ihT + (size_t)id * H3;
        const float xr = xrow[j]            + b_ih[j];
        const float xz = xrow[HID + j]      + b_ih[HID + j];
        const float xn = xrow[2 * HID + j]  + b_ih[2 * HID + j];
        const float hr  = sr + b_hh[j];
        const float hz  = sz + b_hh[HID + j];
        const float hn_ = sn + b_hh[2 * HID + j];
        const float rg = 1.f / (1.f + expf(-(xr + hr)));
        const float zg = 1.f / (1.f + expf(-(xz + hz)));
        const float ng = tanhf(xn + rg * hn_);
        const float hp = hprev[(size_t)b * HID + j];
        const float h  = (1.f - zg) * ng + zg * hp;
        hout[(size_t)b * HID + j] = h;
        const unsigned short hh = f2bf(h);
        ohi[(size_t)b * HID + j] = hh;
        olo[(size_t)b * HID + j] = f2bf(h - bf2f(hh));
    }
}

// ---------------------------------------------------------------------------
// Output GEMM, split-bf16 MFMA. C[m][n] = sum_k A[m][k]*B[n][k] + bias[n].
// 128x128 tile, BK=32, LDS pad LDK=40. 4 waves = 2x2 quadrants of 64x64.
// ---------------------------------------------------------------------------
__global__ __launch_bounds__(256) void out_gemm_mfma(
    const unsigned short* __restrict__ Ahi_g,  // 16384 x 1024
    const unsigned short* __restrict__ Alo_g,
    const unsigned short* __restrict__ Bhi_g,  // 4000 x 1024
    const unsigned short* __restrict__ Blo_g,
    const float* __restrict__ bias,
    float* __restrict__ C)
{
    constexpr int BM = 128, BK = 32, LDK = 40;
    __shared__ unsigned short Ah[BM * LDK], Al[BM * LDK];
    __shared__ unsigned short Bh[BM * LDK], Bl[BM * LDK];

    const int tid = threadIdx.x;
    const int l = tid & 63, w = tid >> 6;
    const int wr = w >> 1, wc = w & 1;
    const int col = l & 15, kg = l >> 4;
    const int m0 = blockIdx.x * BM;
    const int n0 = blockIdx.y * BM;

    f32x4 acc[4][4];
    #pragma unroll
    for (int i = 0; i < 4; ++i)
        #pragma unroll
        for (int jt = 0; jt < 4; ++jt)
            acc[i][jt] = (f32x4){0.f, 0.f, 0.f, 0.f};

    for (int kc = 0; kc < HID; kc += BK) {
        __syncthreads();
        #pragma unroll
        for (int i = 0; i < 2; ++i) {
            const int idx = tid + i * 256;          // 0..511
            const int row = idx >> 2, kq = idx & 3;
            const int go = kc + kq * 8;
            *(short8*)(Ah + row * LDK + kq * 8) =
                *(const short8*)(Ahi_g + (size_t)(m0 + row) * HID + go);
            *(short8*)(Al + row * LDK + kq * 8) =
                *(const short8*)(Alo_g + (size_t)(m0 + row) * HID + go);
            const int n = n0 + row;
            short8 vh = {0,0,0,0,0,0,0,0}, vl = {0,0,0,0,0,0,0,0};
            if (n < VOCAB) {
                vh = *(const short8*)(Bhi_g + (size_t)n * HID + go);
                vl = *(const short8*)(Blo_g + (size_t)n * HID + go);
            }
            *(short8*)(Bh + row * LDK + kq * 8) = vh;
            *(short8*)(Bl + row * LDK + kq * 8) = vl;
        }
        __syncthreads();

        short8 af_h[4], af_l[4], bf_h[4], bf_l[4];
        #pragma unroll
        for (int i = 0; i < 4; ++i) {
            const int r = wr * 64 + i * 16 + col;
            af_h[i] = *(const short8*)(Ah + r * LDK + kg * 8);
            af_l[i] = *(const short8*)(Al + r * LDK + kg * 8);
        }
        #pragma unroll
        for (int jt = 0; jt < 4; ++jt) {
            const int r = wc * 64 + jt * 16 + col;
            bf_h[jt] = *(const short8*)(Bh + r * LDK + kg * 8);
            bf_l[jt] = *(const short8*)(Bl + r * LDK + kg * 8);
        }
        #pragma unroll
        for (int i = 0; i < 4; ++i)
            #pragma unroll
            for (int jt = 0; jt < 4; ++jt) {
                acc[i][jt] = __builtin_amdgcn_mfma_f32_16x16x32_bf16(af_h[i], bf_h[jt], acc[i][jt], 0, 0, 0);
                acc[i][jt] = __builtin_amdgcn_mfma_f32_16x16x32_bf16(af_h[i], bf_l[jt], acc[i][jt], 0, 0, 0);
                acc[i][jt] = __builtin_amdgcn_mfma_f32_16x16x32_bf16(af_l[i], bf_h[jt], acc[i][jt], 0, 0, 0);
            }
    }

    #pragma unroll
    for (int i = 0; i < 4; ++i)
        #pragma unroll
        for (int jt = 0; jt < 4; ++jt)
            #pragma unroll
            for (int r = 0; r < 4; ++r) {
                const int m = m0 + wr * 64 + i * 16 + kg * 4 + r;
                const int n = n0 + wc * 64 + jt * 16 + col;
                if (n < VOCAB)
                    C[(size_t)m * VOCAB + n] = acc[i][jt][r] + bias[n];
            }
}

__global__ __launch_bounds__(256) void copy_hn_kernel(
    const float* __restrict__ src, float* __restrict__ dst)
{
    const int i = blockIdx.x * 256 + threadIdx.x;   // 65536 total
    dst[i] = src[i];
}

extern "C" void kernel_launch(void* const* d_in, const int* in_sizes, int n_in,
                              void* d_out, int out_size, void* d_ws, size_t ws_size,
                              hipStream_t stream) {
    const int*   inputs = (const int*)d_in[0];
    const float* h0     = (const float*)d_in[1];
    const float* W_ih   = (const float*)d_in[2];
    const float* W_hh   = (const float*)d_in[3];
    const float* b_ih   = (const float*)d_in[4];
    const float* b_hh   = (const float*)d_in[5];
    const float* W_out  = (const float*)d_in[6];
    const float* b_out  = (const float*)d_in[7];
    float* out = (float*)d_out;

    // workspace layout (bytes)
    char* p = (char*)d_ws;
    unsigned short* ghi     = (unsigned short*)p; p += (size_t)SEQ * BATCH * HID * 2;
    unsigned short* glo     = (unsigned short*)p; p += (size_t)SEQ * BATCH * HID * 2;
    unsigned short* whh_hi  = (unsigned short*)p; p += (size_t)3 * HID * HID * 2;
    unsigned short* whh_lo  = (unsigned short*)p; p += (size_t)3 * HID * HID * 2;
    unsigned short* wout_hi = (unsigned short*)p; p += (size_t)VOCAB * HID * 2;
    unsigned short* wout_lo = (unsigned short*)p; p += (size_t)VOCAB * HID * 2;
    unsigned short* h0_hi   = (unsigned short*)p; p += (size_t)BATCH * HID * 2;
    unsigned short* h0_lo   = (unsigned short*)p; p += (size_t)BATCH * HID * 2;
    float* hb0              = (float*)p;          p += (size_t)BATCH * HID * 4;
    float* hb1              = (float*)p;          p += (size_t)BATCH * HID * 4;
    float* W_ihT            = (float*)p;          p += (size_t)VOCAB * H3 * 4;  // 49 MB

    split_kernel<<<2048, 256, 0, stream>>>(W_hh, W_out, h0,
        whh_hi, whh_lo, wout_hi, wout_lo, h0_hi, h0_lo);
    transpose_wih<<<dim3(VOCAB / 32, H3 / 32), 256, 0, stream>>>(W_ih, W_ihT);

    for (int t = 0; t < SEQ; ++t) {
        const unsigned short* ahi = (t == 0) ? h0_hi : ghi + (size_t)(t - 1) * BATCH * HID;
        const unsigned short* alo = (t == 0) ? h0_lo : glo + (size_t)(t - 1) * BATCH * HID;
        const float* hp = (t == 0) ? h0 : ((t - 1) & 1 ? hb1 : hb0);
        float* ho = (t & 1) ? hb1 : hb0;
        gru_step_mfma<<<256, 512, 0, stream>>>(
            ahi, alo, hp, whh_hi, whh_lo, W_ihT, b_ih, b_hh, inputs,
            ho, ghi + (size_t)t * BATCH * HID, glo + (size_t)t * BATCH * HID, t);
    }

    out_gemm_mfma<<<dim3(128, 32), 256, 0, stream>>>(
        ghi, glo, wout_hi, wout_lo, b_out, out);

    copy_hn_kernel<<<256, 256, 0, stream>>>(
        hb1, out + (size_t)SEQ * BATCH * VOCAB);
}

// Round 4
// 3065.931 us; speedup vs baseline: 4.4996x; 1.0879x over previous
//
#include <hip/hip_runtime.h>
#include <math.h>

#define SEQ 256
#define BATCH 64
#define HID 1024
#define VOCAB 4000
#define H3 (3 * HID)

typedef __attribute__((ext_vector_type(8))) short short8;
typedef __attribute__((ext_vector_type(4))) float f32x4;

__device__ inline unsigned short f2bf(float x) {
    unsigned int u = __builtin_bit_cast(unsigned int, x);
    unsigned int r = (u + 0x7fffu + ((u >> 16) & 1u)) >> 16;   // RNE
    return (unsigned short)r;
}
__device__ inline float bf2f(unsigned short h) {
    unsigned int u = ((unsigned int)h) << 16;
    return __builtin_bit_cast(float, u);
}

// ---------------------------------------------------------------------------
// Split f32 arrays into bf16 hi/lo pairs (W_hh, W_out, h0). Grid-stride.
// ---------------------------------------------------------------------------
__global__ __launch_bounds__(256) void split_kernel(
    const float* __restrict__ W_hh, const float* __restrict__ W_out,
    const float* __restrict__ h0,
    unsigned short* __restrict__ whh_hi, unsigned short* __restrict__ whh_lo,
    unsigned short* __restrict__ wout_hi, unsigned short* __restrict__ wout_lo,
    unsigned short* __restrict__ h0_hi, unsigned short* __restrict__ h0_lo)
{
    const int NW = 3 * HID * HID;
    const int NO = VOCAB * HID;
    const int NH = BATCH * HID;
    const int total = NW + NO + NH;
    for (int i = blockIdx.x * blockDim.x + threadIdx.x; i < total;
         i += gridDim.x * blockDim.x) {
        const float* src; unsigned short *dh, *dl; int off;
        if (i < NW)           { src = W_hh;  dh = whh_hi;  dl = whh_lo;  off = i; }
        else if (i < NW + NO) { src = W_out; dh = wout_hi; dl = wout_lo; off = i - NW; }
        else                  { src = h0;    dh = h0_hi;   dl = h0_lo;   off = i - NW - NO; }
        float x = src[off];
        unsigned short hi = f2bf(x);
        dh[off] = hi;
        dl[off] = f2bf(x - bf2f(hi));
    }
}

// ---------------------------------------------------------------------------
// W_ih (3072 x 4000) -> W_ihT (4000 x 3072), 32x32 LDS tiles.
// ---------------------------------------------------------------------------
__global__ __launch_bounds__(256) void transpose_wih(
    const float* __restrict__ W_ih, float* __restrict__ W_ihT)
{
    __shared__ float tile[32][33];
    const int tx = threadIdx.x & 31;
    const int ty = threadIdx.x >> 5;          // 0..7
    const int r0 = blockIdx.y * 32;           // 3072-dim base
    const int c0 = blockIdx.x * 32;           // 4000-dim base
    #pragma unroll
    for (int k = 0; k < 4; ++k) {
        const int r = ty + k * 8;
        tile[r][tx] = W_ih[(size_t)(r0 + r) * VOCAB + c0 + tx];  // 4000%32==0
    }
    __syncthreads();
    #pragma unroll
    for (int k = 0; k < 4; ++k) {
        const int r = ty + k * 8;
        W_ihT[(size_t)(c0 + r) * H3 + r0 + tx] = tile[tx][r];
    }
}

// ---------------------------------------------------------------------------
// GRU step via MFMA, K-split across 8 waves. Grid = 256 blocks x 512 threads.
// XCD-aware swizzle: with default dispatch (bid -> XCD bid%8), XCD x always
// owns j-tiles [8x, 8x+8) x all 4 m-tiles. Weight slice per XCD = 8 * 196 KB
// = 1.57 MB -> L2-resident ACROSS the 256 identical launches (weights are
// re-read from the same XCD's L2 every step instead of L3).
// ---------------------------------------------------------------------------
__global__ __launch_bounds__(512) void gru_step_mfma(
    const unsigned short* __restrict__ ahi,   // h_{t-1} hi (64x1024)
    const unsigned short* __restrict__ alo,
    const float* __restrict__ hprev,          // h_{t-1} f32
    const unsigned short* __restrict__ whh_hi,
    const unsigned short* __restrict__ whh_lo,
    const float* __restrict__ W_ihT,          // (4000, 3072)
    const float* __restrict__ b_ih,
    const float* __restrict__ b_hh,
    const int*   __restrict__ ids,
    float* __restrict__ hout,                 // h_t f32
    unsigned short* __restrict__ ohi,
    unsigned short* __restrict__ olo,
    int t)
{
    __shared__ float red[8][3][64][4];        // [wave][gate][lane][reg] 24 KB

    const int tid = threadIdx.x;
    const int w   = tid >> 6;                 // 0..7
    const int l   = tid & 63;
    // XCD-aware remap: xcd = bid&7 (round-robin dispatch), local = bid>>3
    const int bid   = blockIdx.x;
    const int xcd   = bid & 7;
    const int local = bid >> 3;               // 0..31
    const int jt    = xcd * 8 + (local >> 2); // 0..63
    const int mt    = local & 3;              // 0..3
    const int j0  = jt * 16, m0 = mt * 16;
    const int col = l & 15, kg = l >> 4;

    f32x4 accr = {0.f, 0.f, 0.f, 0.f};
    f32x4 accz = {0.f, 0.f, 0.f, 0.f};
    f32x4 accn = {0.f, 0.f, 0.f, 0.f};

    const size_t arow   = (size_t)(m0 + col) * HID;
    const size_t brow_r = (size_t)(j0 + col) * HID;
    const size_t brow_z = (size_t)(HID + j0 + col) * HID;
    const size_t brow_n = (size_t)(2 * HID + j0 + col) * HID;

    const int kbase = w * 128 + kg * 8;
    #pragma unroll 2
    for (int c = 0; c < 4; ++c) {
        const int ko = kbase + c * 32;
        short8 a_h  = *(const short8*)(ahi + arow + ko);
        short8 a_l  = *(const short8*)(alo + arow + ko);
        short8 br_h = *(const short8*)(whh_hi + brow_r + ko);
        short8 br_l = *(const short8*)(whh_lo + brow_r + ko);
        short8 bz_h = *(const short8*)(whh_hi + brow_z + ko);
        short8 bz_l = *(const short8*)(whh_lo + brow_z + ko);
        short8 bn_h = *(const short8*)(whh_hi + brow_n + ko);
        short8 bn_l = *(const short8*)(whh_lo + brow_n + ko);

        accr = __builtin_amdgcn_mfma_f32_16x16x32_bf16(a_h, br_h, accr, 0, 0, 0);
        accr = __builtin_amdgcn_mfma_f32_16x16x32_bf16(a_h, br_l, accr, 0, 0, 0);
        accr = __builtin_amdgcn_mfma_f32_16x16x32_bf16(a_l, br_h, accr, 0, 0, 0);

        accz = __builtin_amdgcn_mfma_f32_16x16x32_bf16(a_h, bz_h, accz, 0, 0, 0);
        accz = __builtin_amdgcn_mfma_f32_16x16x32_bf16(a_h, bz_l, accz, 0, 0, 0);
        accz = __builtin_amdgcn_mfma_f32_16x16x32_bf16(a_l, bz_h, accz, 0, 0, 0);

        accn = __builtin_amdgcn_mfma_f32_16x16x32_bf16(a_h, bn_h, accn, 0, 0, 0);
        accn = __builtin_amdgcn_mfma_f32_16x16x32_bf16(a_h, bn_l, accn, 0, 0, 0);
        accn = __builtin_amdgcn_mfma_f32_16x16x32_bf16(a_l, bn_h, accn, 0, 0, 0);
    }

    *(f32x4*)&red[w][0][l][0] = accr;
    *(f32x4*)&red[w][1][l][0] = accz;
    *(f32x4*)&red[w][2][l][0] = accn;
    __syncthreads();

    if (tid < 256) {
        const int bi   = tid >> 4;            // 0..15 (batch within tile)
        const int cj   = tid & 15;            // j within tile
        const int lane = (bi >> 2) * 16 + cj; // MFMA C-layout inverse
        const int rr   = bi & 3;
        float sr = 0.f, sz = 0.f, sn = 0.f;
        #pragma unroll
        for (int ww = 0; ww < 8; ++ww) {
            sr += red[ww][0][lane][rr];
            sz += red[ww][1][lane][rr];
            sn += red[ww][2][lane][rr];
        }
        const int b = m0 + bi;
        const int j = j0 + cj;
        const int id = ids[b * SEQ + t];
        const float* xrow = W_ihT + (size_t)id * H3;
        const float xr = xrow[j]            + b_ih[j];
        const float xz = xrow[HID + j]      + b_ih[HID + j];
        const float xn = xrow[2 * HID + j]  + b_ih[2 * HID + j];
        const float hr  = sr + b_hh[j];
        const float hz  = sz + b_hh[HID + j];
        const float hn_ = sn + b_hh[2 * HID + j];
        const float rg = 1.f / (1.f + expf(-(xr + hr)));
        const float zg = 1.f / (1.f + expf(-(xz + hz)));
        const float ng = tanhf(xn + rg * hn_);
        const float hp = hprev[(size_t)b * HID + j];
        const float h  = (1.f - zg) * ng + zg * hp;
        hout[(size_t)b * HID + j] = h;
        const unsigned short hh = f2bf(h);
        ohi[(size_t)b * HID + j] = hh;
        olo[(size_t)b * HID + j] = f2bf(h - bf2f(hh));
    }
}

// ---------------------------------------------------------------------------
// Output GEMM, split-bf16 MFMA. 1D grid 4096 blocks, XCD-aware: XCD x owns
// n-tiles [4x, 4x+4) x all 128 m-tiles -> B panels 2 MB/XCD L2-resident.
// ---------------------------------------------------------------------------
__global__ __launch_bounds__(256) void out_gemm_mfma(
    const unsigned short* __restrict__ Ahi_g,  // 16384 x 1024
    const unsigned short* __restrict__ Alo_g,
    const unsigned short* __restrict__ Bhi_g,  // 4000 x 1024
    const unsigned short* __restrict__ Blo_g,
    const float* __restrict__ bias,
    float* __restrict__ C)
{
    constexpr int BM = 128, BK = 32, LDK = 40;
    __shared__ unsigned short Ah[BM * LDK], Al[BM * LDK];
    __shared__ unsigned short Bh[BM * LDK], Bl[BM * LDK];

    const int tid = threadIdx.x;
    const int l = tid & 63, w = tid >> 6;
    const int wr = w >> 1, wc = w & 1;
    const int col = l & 15, kg = l >> 4;
    // XCD-aware: xcd = bid&7, q = bid>>3 in [0,512): y = xcd*4 + q>>7, x = q&127
    const int bid = blockIdx.x;
    const int xcd = bid & 7;
    const int q   = bid >> 3;
    const int yb  = xcd * 4 + (q >> 7);       // 0..31 (n-tile)
    const int xb  = q & 127;                  // 0..127 (m-tile)
    const int m0 = xb * BM;
    const int n0 = yb * BM;

    f32x4 acc[4][4];
    #pragma unroll
    for (int i = 0; i < 4; ++i)
        #pragma unroll
        for (int jt = 0; jt < 4; ++jt)
            acc[i][jt] = (f32x4){0.f, 0.f, 0.f, 0.f};

    for (int kc = 0; kc < HID; kc += BK) {
        __syncthreads();
        #pragma unroll
        for (int i = 0; i < 2; ++i) {
            const int idx = tid + i * 256;          // 0..511
            const int row = idx >> 2, kq = idx & 3;
            const int go = kc + kq * 8;
            *(short8*)(Ah + row * LDK + kq * 8) =
                *(const short8*)(Ahi_g + (size_t)(m0 + row) * HID + go);
            *(short8*)(Al + row * LDK + kq * 8) =
                *(const short8*)(Alo_g + (size_t)(m0 + row) * HID + go);
            const int n = n0 + row;
            short8 vh = {0,0,0,0,0,0,0,0}, vl = {0,0,0,0,0,0,0,0};
            if (n < VOCAB) {
                vh = *(const short8*)(Bhi_g + (size_t)n * HID + go);
                vl = *(const short8*)(Blo_g + (size_t)n * HID + go);
            }
            *(short8*)(Bh + row * LDK + kq * 8) = vh;
            *(short8*)(Bl + row * LDK + kq * 8) = vl;
        }
        __syncthreads();

        short8 af_h[4], af_l[4], bf_h[4], bf_l[4];
        #pragma unroll
        for (int i = 0; i < 4; ++i) {
            const int r = wr * 64 + i * 16 + col;
            af_h[i] = *(const short8*)(Ah + r * LDK + kg * 8);
            af_l[i] = *(const short8*)(Al + r * LDK + kg * 8);
        }
        #pragma unroll
        for (int jt = 0; jt < 4; ++jt) {
            const int r = wc * 64 + jt * 16 + col;
            bf_h[jt] = *(const short8*)(Bh + r * LDK + kg * 8);
            bf_l[jt] = *(const short8*)(Bl + r * LDK + kg * 8);
        }
        #pragma unroll
        for (int i = 0; i < 4; ++i)
            #pragma unroll
            for (int jt = 0; jt < 4; ++jt) {
                acc[i][jt] = __builtin_amdgcn_mfma_f32_16x16x32_bf16(af_h[i], bf_h[jt], acc[i][jt], 0, 0, 0);
                acc[i][jt] = __builtin_amdgcn_mfma_f32_16x16x32_bf16(af_h[i], bf_l[jt], acc[i][jt], 0, 0, 0);
                acc[i][jt] = __builtin_amdgcn_mfma_f32_16x16x32_bf16(af_l[i], bf_h[jt], acc[i][jt], 0, 0, 0);
            }
    }

    #pragma unroll
    for (int i = 0; i < 4; ++i)
        #pragma unroll
        for (int jt = 0; jt < 4; ++jt)
            #pragma unroll
            for (int r = 0; r < 4; ++r) {
                const int m = m0 + wr * 64 + i * 16 + kg * 4 + r;
                const int n = n0 + wc * 64 + jt * 16 + col;
                if (n < VOCAB)
                    C[(size_t)m * VOCAB + n] = acc[i][jt][r] + bias[n];
            }
}

__global__ __launch_bounds__(256) void copy_hn_kernel(
    const float* __restrict__ src, float* __restrict__ dst)
{
    const int i = blockIdx.x * 256 + threadIdx.x;   // 65536 total
    dst[i] = src[i];
}

extern "C" void kernel_launch(void* const* d_in, const int* in_sizes, int n_in,
                              void* d_out, int out_size, void* d_ws, size_t ws_size,
                              hipStream_t stream) {
    const int*   inputs = (const int*)d_in[0];
    const float* h0     = (const float*)d_in[1];
    const float* W_ih   = (const float*)d_in[2];
    const float* W_hh   = (const float*)d_in[3];
    const float* b_ih   = (const float*)d_in[4];
    const float* b_hh   = (const float*)d_in[5];
    const float* W_out  = (const float*)d_in[6];
    const float* b_out  = (const float*)d_in[7];
    float* out = (float*)d_out;

    // workspace layout (bytes)
    char* p = (char*)d_ws;
    unsigned short* ghi     = (unsigned short*)p; p += (size_t)SEQ * BATCH * HID * 2;
    unsigned short* glo     = (unsigned short*)p; p += (size_t)SEQ * BATCH * HID * 2;
    unsigned short* whh_hi  = (unsigned short*)p; p += (size_t)3 * HID * HID * 2;
    unsigned short* whh_lo  = (unsigned short*)p; p += (size_t)3 * HID * HID * 2;
    unsigned short* wout_hi = (unsigned short*)p; p += (size_t)VOCAB * HID * 2;
    unsigned short* wout_lo = (unsigned short*)p; p += (size_t)VOCAB * HID * 2;
    unsigned short* h0_hi   = (unsigned short*)p; p += (size_t)BATCH * HID * 2;
    unsigned short* h0_lo   = (unsigned short*)p; p += (size_t)BATCH * HID * 2;
    float* hb0              = (float*)p;          p += (size_t)BATCH * HID * 4;
    float* hb1              = (float*)p;          p += (size_t)BATCH * HID * 4;
    float* W_ihT            = (float*)p;          p += (size_t)VOCAB * H3 * 4;  // 49 MB

    split_kernel<<<2048, 256, 0, stream>>>(W_hh, W_out, h0,
        whh_hi, whh_lo, wout_hi, wout_lo, h0_hi, h0_lo);
    transpose_wih<<<dim3(VOCAB / 32, H3 / 32), 256, 0, stream>>>(W_ih, W_ihT);

    for (int t = 0; t < SEQ; ++t) {
        const unsigned short* ahi = (t == 0) ? h0_hi : ghi + (size_t)(t - 1) * BATCH * HID;
        const unsigned short* alo = (t == 0) ? h0_lo : glo + (size_t)(t - 1) * BATCH * HID;
        const float* hp = (t == 0) ? h0 : ((t - 1) & 1 ? hb1 : hb0);
        float* ho = (t & 1) ? hb1 : hb0;
        gru_step_mfma<<<256, 512, 0, stream>>>(
            ahi, alo, hp, whh_hi, whh_lo, W_ihT, b_ih, b_hh, inputs,
            ho, ghi + (size_t)t * BATCH * HID, glo + (size_t)t * BATCH * HID, t);
    }

    out_gemm_mfma<<<4096, 256, 0, stream>>>(
        ghi, glo, wout_hi, wout_lo, b_out, out);

    copy_hn_kernel<<<256, 256, 0, stream>>>(
        hb1, out + (size_t)SEQ * BATCH * VOCAB);
}

// Round 5
// 2602.091 us; speedup vs baseline: 5.3017x; 1.1783x over previous
//
#include <hip/hip_runtime.h>
#include <math.h>

#define SEQ 256
#define BATCH 64
#define HID 1024
#define VOCAB 4000
#define H3 (3 * HID)
#define HSLICE (BATCH * HID)

typedef __attribute__((ext_vector_type(8))) short short8;
typedef __attribute__((ext_vector_type(4))) float f32x4;

__device__ inline unsigned short f2bf(float x) {
    unsigned int u = __builtin_bit_cast(unsigned int, x);
    unsigned int r = (u + 0x7fffu + ((u >> 16) & 1u)) >> 16;   // RNE
    return (unsigned short)r;
}
__device__ inline float bf2f(unsigned short h) {
    unsigned int u = ((unsigned int)h) << 16;
    return __builtin_bit_cast(float, u);
}

// ---------------------------------------------------------------------------
// Split f32 arrays into bf16 hi/lo pairs. h0 goes into slice 0 of the
// h-history (so the persistent kernel has no t==0 special case).
// ---------------------------------------------------------------------------
__global__ __launch_bounds__(256) void split_kernel(
    const float* __restrict__ W_hh, const float* __restrict__ W_out,
    const float* __restrict__ h0,
    unsigned short* __restrict__ whh_hi, unsigned short* __restrict__ whh_lo,
    unsigned short* __restrict__ wout_hi, unsigned short* __restrict__ wout_lo,
    unsigned short* __restrict__ h0_hi, unsigned short* __restrict__ h0_lo)
{
    const int NW = 3 * HID * HID;
    const int NO = VOCAB * HID;
    const int NH = BATCH * HID;
    const int total = NW + NO + NH;
    for (int i = blockIdx.x * blockDim.x + threadIdx.x; i < total;
         i += gridDim.x * blockDim.x) {
        const float* src; unsigned short *dh, *dl; int off;
        if (i < NW)           { src = W_hh;  dh = whh_hi;  dl = whh_lo;  off = i; }
        else if (i < NW + NO) { src = W_out; dh = wout_hi; dl = wout_lo; off = i - NW; }
        else                  { src = h0;    dh = h0_hi;   dl = h0_lo;   off = i - NW - NO; }
        float x = src[off];
        unsigned short hi = f2bf(x);
        dh[off] = hi;
        dl[off] = f2bf(x - bf2f(hi));
    }
}

// ---------------------------------------------------------------------------
// W_ih (3072 x 4000) -> W_ihT (4000 x 3072), 32x32 LDS tiles.
// ---------------------------------------------------------------------------
__global__ __launch_bounds__(256) void transpose_wih(
    const float* __restrict__ W_ih, float* __restrict__ W_ihT)
{
    __shared__ float tile[32][33];
    const int tx = threadIdx.x & 31;
    const int ty = threadIdx.x >> 5;          // 0..7
    const int r0 = blockIdx.y * 32;           // 3072-dim base
    const int c0 = blockIdx.x * 32;           // 4000-dim base
    #pragma unroll
    for (int k = 0; k < 4; ++k) {
        const int r = ty + k * 8;
        tile[r][tx] = W_ih[(size_t)(r0 + r) * VOCAB + c0 + tx];  // 4000%32==0
    }
    __syncthreads();
    #pragma unroll
    for (int k = 0; k < 4; ++k) {
        const int r = ty + k * 8;
        W_ihT[(size_t)(c0 + r) * H3 + r0 + tx] = tile[tx][r];
    }
}

__global__ void zero_barrier(int* b) { b[threadIdx.x] = 0; }   // 512 ints

// ---------------------------------------------------------------------------
// Persistent cooperative GRU: all 256 steps in one kernel.
// 256 blocks x 512 threads (1 block/CU, co-resident via coop launch).
// Block: jt = (bid&7)*8 + (local>>2), mt = local&3 (XCD-stable weight slice).
// Per step: 8-wave K-split MFMA partials -> LDS reduce -> epilogue (256 thr,
// h in registers, x_proj prefetched one step ahead) -> two-level grid barrier.
// Barrier release = agent fence (wbl2, NO invalidate) by block leader only:
// h history coherent via LLC; weights remain L2-resident across steps.
// ---------------------------------------------------------------------------
__global__ __launch_bounds__(512) void gru_persist(
    const unsigned short* __restrict__ whh_hi,
    const unsigned short* __restrict__ whh_lo,
    const float* __restrict__ W_ihT,
    const float* __restrict__ b_ih,
    const float* __restrict__ b_hh,
    const float* __restrict__ h0,
    const int* __restrict__ ids,
    unsigned short* ghi,                 // (SEQ+1) slices of 64x1024
    unsigned short* glo,
    float* hn_out,                       // d_out tail (64x1024)
    int* bar)
{
    __shared__ float red[8][3][64][4];   // 24 KB

    const int tid = threadIdx.x;
    const int w   = tid >> 6;
    const int l   = tid & 63;
    const int bid = blockIdx.x;
    const int grp   = bid & 7;
    const int local = bid >> 3;
    const int jt = grp * 8 + (local >> 2);
    const int mt = local & 3;
    const int j0 = jt * 16, m0 = mt * 16;
    const int col = l & 15, kg = l >> 4;

    const size_t arow   = (size_t)(m0 + col) * HID;
    const size_t brow_r = (size_t)(j0 + col) * HID;
    const size_t brow_z = (size_t)(HID + j0 + col) * HID;
    const size_t brow_n = (size_t)(2 * HID + j0 + col) * HID;
    const int kbase = w * 128 + kg * 8;

    // epilogue-thread persistent state (valid for tid < 256)
    const int bi = (tid >> 4) & 15;
    const int cj = tid & 15;
    const int eb = m0 + bi, ej = j0 + cj;
    float hreg = 0.f, xr_n = 0.f, xz_n = 0.f, xn_n = 0.f;
    float bihr = 0.f, bihz = 0.f, bihn = 0.f;
    float bhhr = 0.f, bhhz = 0.f, bhhn = 0.f;
    if (tid < 256) {
        hreg = h0[(size_t)eb * HID + ej];
        bihr = b_ih[ej]; bihz = b_ih[HID + ej]; bihn = b_ih[2 * HID + ej];
        bhhr = b_hh[ej]; bhhz = b_hh[HID + ej]; bhhn = b_hh[2 * HID + ej];
        const int id0 = ids[eb * SEQ];
        const float* xrow = W_ihT + (size_t)id0 * H3;
        xr_n = xrow[ej]; xz_n = xrow[HID + ej]; xn_n = xrow[2 * HID + ej];
    }

    int* cnt   = bar;            // 8 counters, stride 32 ints (128 B apart)
    int* root  = bar + 256;
    int* epoch = bar + 288;

    for (int t = 0; t < SEQ; ++t) {
        const unsigned short* ah = ghi + (size_t)t * HSLICE;   // h_{t-1} (slice t)
        const unsigned short* al = glo + (size_t)t * HSLICE;

        f32x4 accr = {0.f, 0.f, 0.f, 0.f};
        f32x4 accz = {0.f, 0.f, 0.f, 0.f};
        f32x4 accn = {0.f, 0.f, 0.f, 0.f};

        #pragma unroll
        for (int c = 0; c < 4; ++c) {
            const int ko = kbase + c * 32;
            short8 a_h  = *(const short8*)(ah + arow + ko);
            short8 a_l  = *(const short8*)(al + arow + ko);
            short8 br_h = *(const short8*)(whh_hi + brow_r + ko);
            short8 br_l = *(const short8*)(whh_lo + brow_r + ko);
            short8 bz_h = *(const short8*)(whh_hi + brow_z + ko);
            short8 bz_l = *(const short8*)(whh_lo + brow_z + ko);
            short8 bn_h = *(const short8*)(whh_hi + brow_n + ko);
            short8 bn_l = *(const short8*)(whh_lo + brow_n + ko);

            accr = __builtin_amdgcn_mfma_f32_16x16x32_bf16(a_h, br_h, accr, 0, 0, 0);
            accr = __builtin_amdgcn_mfma_f32_16x16x32_bf16(a_h, br_l, accr, 0, 0, 0);
            accr = __builtin_amdgcn_mfma_f32_16x16x32_bf16(a_l, br_h, accr, 0, 0, 0);

            accz = __builtin_amdgcn_mfma_f32_16x16x32_bf16(a_h, bz_h, accz, 0, 0, 0);
            accz = __builtin_amdgcn_mfma_f32_16x16x32_bf16(a_h, bz_l, accz, 0, 0, 0);
            accz = __builtin_amdgcn_mfma_f32_16x16x32_bf16(a_l, bz_h, accz, 0, 0, 0);

            accn = __builtin_amdgcn_mfma_f32_16x16x32_bf16(a_h, bn_h, accn, 0, 0, 0);
            accn = __builtin_amdgcn_mfma_f32_16x16x32_bf16(a_h, bn_l, accn, 0, 0, 0);
            accn = __builtin_amdgcn_mfma_f32_16x16x32_bf16(a_l, bn_h, accn, 0, 0, 0);
        }

        *(f32x4*)&red[w][0][l][0] = accr;
        *(f32x4*)&red[w][1][l][0] = accz;
        *(f32x4*)&red[w][2][l][0] = accn;
        __syncthreads();

        if (tid < 256) {
            const int lane = (bi >> 2) * 16 + cj;   // MFMA C-layout inverse
            const int rr   = bi & 3;
            float sr = 0.f, sz = 0.f, sn = 0.f;
            #pragma unroll
            for (int ww = 0; ww < 8; ++ww) {
                sr += red[ww][0][lane][rr];
                sz += red[ww][1][lane][rr];
                sn += red[ww][2][lane][rr];
            }
            const float xr = xr_n + bihr;
            const float xz = xz_n + bihz;
            const float xn = xn_n + bihn;
            const float hr  = sr + bhhr;
            const float hz  = sz + bhhz;
            const float hn_ = sn + bhhn;
            const float rg = 1.f / (1.f + expf(-(xr + hr)));
            const float zg = 1.f / (1.f + expf(-(xz + hz)));
            const float ng = tanhf(xn + rg * hn_);
            hreg = (1.f - zg) * ng + zg * hreg;

            const size_t ho = (size_t)(t + 1) * HSLICE + (size_t)eb * HID + ej;
            const unsigned short hh = f2bf(hreg);
            ghi[ho] = hh;
            glo[ho] = f2bf(hreg - bf2f(hh));

            if (t + 1 < SEQ) {                       // prefetch next x_proj row
                const int id2 = ids[eb * SEQ + t + 1];
                const float* xrow = W_ihT + (size_t)id2 * H3;
                xr_n = xrow[ej]; xz_n = xrow[HID + ej]; xn_n = xrow[2 * HID + ej];
            } else {
                hn_out[(size_t)eb * HID + ej] = hreg;
            }
        }

        // ---- two-level grid barrier (L2-preserving) ----
        __syncthreads();                  // all stores drained to L2
        if (tid == 0) {
            __builtin_amdgcn_fence(__ATOMIC_RELEASE, "agent");   // wbl2, no inv
            const int v = atomicAdd(&cnt[grp * 32], 1) + 1;
            if (v == (t + 1) * 32) {
                const int d = atomicAdd(root, 1) + 1;
                if (d == (t + 1) * 8)
                    __hip_atomic_store(epoch, t + 1, __ATOMIC_RELAXED,
                                       __HIP_MEMORY_SCOPE_AGENT);
            }
            while (__hip_atomic_load(epoch, __ATOMIC_RELAXED,
                                     __HIP_MEMORY_SCOPE_AGENT) < t + 1)
                __builtin_amdgcn_s_sleep(1);
        }
        __syncthreads();
    }
}

// ---------------------------------------------------------------------------
// Output GEMM, split-bf16 MFMA. 1D grid 4096 blocks, XCD-aware stripes.
// ---------------------------------------------------------------------------
__global__ __launch_bounds__(256) void out_gemm_mfma(
    const unsigned short* __restrict__ Ahi_g,  // 16384 x 1024
    const unsigned short* __restrict__ Alo_g,
    const unsigned short* __restrict__ Bhi_g,  // 4000 x 1024
    const unsigned short* __restrict__ Blo_g,
    const float* __restrict__ bias,
    float* __restrict__ C)
{
    constexpr int BM = 128, BK = 32, LDK = 40;
    __shared__ unsigned short Ah[BM * LDK], Al[BM * LDK];
    __shared__ unsigned short Bh[BM * LDK], Bl[BM * LDK];

    const int tid = threadIdx.x;
    const int l = tid & 63, w = tid >> 6;
    const int wr = w >> 1, wc = w & 1;
    const int col = l & 15, kg = l >> 4;
    const int bid = blockIdx.x;
    const int xcd = bid & 7;
    const int q   = bid >> 3;
    const int yb  = xcd * 4 + (q >> 7);       // 0..31 (n-tile)
    const int xb  = q & 127;                  // 0..127 (m-tile)
    const int m0 = xb * BM;
    const int n0 = yb * BM;

    f32x4 acc[4][4];
    #pragma unroll
    for (int i = 0; i < 4; ++i)
        #pragma unroll
        for (int jt = 0; jt < 4; ++jt)
            acc[i][jt] = (f32x4){0.f, 0.f, 0.f, 0.f};

    for (int kc = 0; kc < HID; kc += BK) {
        __syncthreads();
        #pragma unroll
        for (int i = 0; i < 2; ++i) {
            const int idx = tid + i * 256;          // 0..511
            const int row = idx >> 2, kq = idx & 3;
            const int go = kc + kq * 8;
            *(short8*)(Ah + row * LDK + kq * 8) =
                *(const short8*)(Ahi_g + (size_t)(m0 + row) * HID + go);
            *(short8*)(Al + row * LDK + kq * 8) =
                *(const short8*)(Alo_g + (size_t)(m0 + row) * HID + go);
            const int n = n0 + row;
            short8 vh = {0,0,0,0,0,0,0,0}, vl = {0,0,0,0,0,0,0,0};
            if (n < VOCAB) {
                vh = *(const short8*)(Bhi_g + (size_t)n * HID + go);
                vl = *(const short8*)(Blo_g + (size_t)n * HID + go);
            }
            *(short8*)(Bh + row * LDK + kq * 8) = vh;
            *(short8*)(Bl + row * LDK + kq * 8) = vl;
        }
        __syncthreads();

        short8 af_h[4], af_l[4], bf_h[4], bf_l[4];
        #pragma unroll
        for (int i = 0; i < 4; ++i) {
            const int r = wr * 64 + i * 16 + col;
            af_h[i] = *(const short8*)(Ah + r * LDK + kg * 8);
            af_l[i] = *(const short8*)(Al + r * LDK + kg * 8);
        }
        #pragma unroll
        for (int jt = 0; jt < 4; ++jt) {
            const int r = wc * 64 + jt * 16 + col;
            bf_h[jt] = *(const short8*)(Bh + r * LDK + kg * 8);
            bf_l[jt] = *(const short8*)(Bl + r * LDK + kg * 8);
        }
        #pragma unroll
        for (int i = 0; i < 4; ++i)
            #pragma unroll
            for (int jt = 0; jt < 4; ++jt) {
                acc[i][jt] = __builtin_amdgcn_mfma_f32_16x16x32_bf16(af_h[i], bf_h[jt], acc[i][jt], 0, 0, 0);
                acc[i][jt] = __builtin_amdgcn_mfma_f32_16x16x32_bf16(af_h[i], bf_l[jt], acc[i][jt], 0, 0, 0);
                acc[i][jt] = __builtin_amdgcn_mfma_f32_16x16x32_bf16(af_l[i], bf_h[jt], acc[i][jt], 0, 0, 0);
            }
    }

    #pragma unroll
    for (int i = 0; i < 4; ++i)
        #pragma unroll
        for (int jt = 0; jt < 4; ++jt)
            #pragma unroll
            for (int r = 0; r < 4; ++r) {
                const int m = m0 + wr * 64 + i * 16 + kg * 4 + r;
                const int n = n0 + wc * 64 + jt * 16 + col;
                if (n < VOCAB)
                    C[(size_t)m * VOCAB + n] = acc[i][jt][r] + bias[n];
            }
}

extern "C" void kernel_launch(void* const* d_in, const int* in_sizes, int n_in,
                              void* d_out, int out_size, void* d_ws, size_t ws_size,
                              hipStream_t stream) {
    const int*   inputs = (const int*)d_in[0];
    const float* h0     = (const float*)d_in[1];
    const float* W_ih   = (const float*)d_in[2];
    const float* W_hh   = (const float*)d_in[3];
    const float* b_ih   = (const float*)d_in[4];
    const float* b_hh   = (const float*)d_in[5];
    const float* W_out  = (const float*)d_in[6];
    const float* b_out  = (const float*)d_in[7];
    float* out = (float*)d_out;

    // workspace layout
    char* p = (char*)d_ws;
    unsigned short* ghi     = (unsigned short*)p; p += (size_t)(SEQ + 1) * HSLICE * 2;
    unsigned short* glo     = (unsigned short*)p; p += (size_t)(SEQ + 1) * HSLICE * 2;
    unsigned short* whh_hi  = (unsigned short*)p; p += (size_t)3 * HID * HID * 2;
    unsigned short* whh_lo  = (unsigned short*)p; p += (size_t)3 * HID * HID * 2;
    unsigned short* wout_hi = (unsigned short*)p; p += (size_t)VOCAB * HID * 2;
    unsigned short* wout_lo = (unsigned short*)p; p += (size_t)VOCAB * HID * 2;
    float* W_ihT            = (float*)p;          p += (size_t)VOCAB * H3 * 4;
    int* bar                = (int*)p;            p += 512 * 4;

    split_kernel<<<2048, 256, 0, stream>>>(W_hh, W_out, h0,
        whh_hi, whh_lo, wout_hi, wout_lo, ghi /*slice 0*/, glo /*slice 0*/);
    transpose_wih<<<dim3(VOCAB / 32, H3 / 32), 256, 0, stream>>>(W_ih, W_ihT);
    zero_barrier<<<1, 512, 0, stream>>>(bar);

    float* hn_out = out + (size_t)SEQ * BATCH * VOCAB;
    const unsigned short* a_whh_hi = whh_hi;
    const unsigned short* a_whh_lo = whh_lo;
    const float* a_wihT = W_ihT;
    const float* a_bih = b_ih;
    const float* a_bhh = b_hh;
    const float* a_h0 = h0;
    const int* a_ids = inputs;
    unsigned short* a_ghi = ghi;
    unsigned short* a_glo = glo;
    int* a_bar = bar;
    void* kargs[] = { (void*)&a_whh_hi, (void*)&a_whh_lo, (void*)&a_wihT,
                      (void*)&a_bih, (void*)&a_bhh, (void*)&a_h0, (void*)&a_ids,
                      (void*)&a_ghi, (void*)&a_glo, (void*)&hn_out, (void*)&a_bar };
    hipLaunchCooperativeKernel((const void*)gru_persist, dim3(256), dim3(512),
                               kargs, 0, stream);

    out_gemm_mfma<<<4096, 256, 0, stream>>>(
        ghi + HSLICE, glo + HSLICE, wout_hi, wout_lo, b_out, out);
}